// Round 7
// baseline (1330.115 us; speedup 1.0000x reference)
//
#include <hip/hip_runtime.h>

// Problem constants (match reference)
#define SEQ 2048
#define BAT 256
#define KD  64
#define HD  128

typedef _Float16 half2v  __attribute__((ext_vector_type(2)));  // builtin fdot2 type
typedef __fp16   fp16x2  __attribute__((ext_vector_type(2)));  // cvt_pkrtz return type

// ds_swizzle xor patterns (BitMode: (xor<<10)|(or<<5)|and, and=0x1F)
template<int PAT>
__device__ __forceinline__ float swz(float x) {
    return __int_as_float(__builtin_amdgcn_ds_swizzle(__float_as_int(x), PAT));
}
#define XOR4 0x101F

// DPP helpers. CTRL: 0xB1 = quad_perm(1,0,3,2) = lane^1; 0x4E = quad_perm(2,3,0,1)
// = lane^2; 0x128 = row_ror:8 = lane^8 within a 16-lane row (rot-8 in 16 == xor8).
template<int CTRL>
__device__ __forceinline__ float dpp_add(float keep, float send) {
    const int r = __builtin_amdgcn_update_dpp(0, __float_as_int(send),
                                              CTRL, 0xF, 0xF, true);
    return keep + __int_as_float(r);
}
template<int CTRL>
__device__ __forceinline__ float dpp_mov(float send) {
    const int r = __builtin_amdgcn_update_dpp(0, __float_as_int(send),
                                              CTRL, 0xF, 0xF, true);
    return __int_as_float(r);
}

// Pack two f32 -> f16x2 bits (v_cvt_pkrtz_f16_f32).
__device__ __forceinline__ int PK(float a, float b) {
    fp16x2 p = __builtin_amdgcn_cvt_pkrtz(a, b);
    return __builtin_bit_cast(int, p);
}

// f32 += dot2(f16x2, f16x2) — v_dot2_f32_f16 (2 MACs / inst), f32 accumulate.
__device__ __forceinline__ float fdot2(int w, int h, float c) {
#if __has_builtin(__builtin_amdgcn_fdot2)
    return __builtin_amdgcn_fdot2(__builtin_bit_cast(half2v, w),
                                  __builtin_bit_cast(half2v, h), c, false);
#else
    half2v wv = __builtin_bit_cast(half2v, w), hv = __builtin_bit_cast(half2v, h);
    return fmaf((float)wv[1], (float)hv[1], fmaf((float)wv[0], (float)hv[0], c));
#endif
}

// Pin a scalar into a register (loads can't sink past the volatile asm).
#define PIN(x) asm volatile("" : "+v"(x))

// LDS-visibility-only barrier: does NOT drain vmcnt (global stores stay in
// flight; they need no ordering with the barrier).
#define STEP_BARRIER() do {                                   \
    asm volatile("s_waitcnt lgkmcnt(0)" ::: "memory");        \
    __builtin_amdgcn_s_barrier();                             \
    asm volatile("" ::: "memory");                            \
} while (0)

// ---------------------------------------------------------------------------
// Kernel 1: precompute type-dependent tables into d_ws (f32).
//   tabH[ty][r] = sum_k embed_W[ty][k]*W_ih[r][k] + b_ih[r] + b_hh[r]
//   tabD[ty][r] = sum_k embed_W[ty][k]*dec_W[r][k] + dec_b[r]
// ---------------------------------------------------------------------------
__global__ __launch_bounds__(128) void precompute_tables(
    const float* __restrict__ embed_W, const float* __restrict__ W_ih,
    const float* __restrict__ b_ih,    const float* __restrict__ b_hh,
    const float* __restrict__ dec_W,   const float* __restrict__ dec_b,
    float* __restrict__ tabH, float* __restrict__ tabD)
{
    __shared__ float x[KD];
    const int ty = blockIdx.x;   // 0..64 (row 64 = padding, embed row is zero)
    const int r  = threadIdx.x;  // 0..127
    if (r < KD) x[r] = embed_W[ty * KD + r];
    __syncthreads();
    float ah = 0.f, ad = 0.f;
#pragma unroll
    for (int k = 0; k < KD; ++k) {
        const float xv = x[k];
        ah += xv * W_ih[r * KD + k];
        ad += xv * dec_W[r * (KD + HD) + k];
    }
    tabH[ty * HD + r] = ah + b_ih[r] + b_hh[r];
    tabD[ty * HD + r] = ad + dec_b[r];
}

// ---------------------------------------------------------------------------
// Kernel 2: persistent per-batch-element recurrence. One WG per batch element,
// 512 threads = 8 waves. Per step, lane (c = tid&15, g = tid>>4) computes
// partial dots for BOTH matrices (hidden + decay), rows 4g..4g+3, over h
// chunk [8c, 8c+8) — 8 accumulators, 32 v_dot2_f32_f16 (f16x2 weights in 32
// pinned regs, h read as ONE ds_read_b128 of f16).
// Reduction over the 16 chunk lanes (c bits b0..b3):
//   xor1 (DPP quad), xor2 (DPP quad), xor8 (DPP row_ror:8), xor4 (ds_swizzle)
// leaving lane (b3,b2,b1,b0) the full preact for type=b3 (0=hidden,1=decay),
// row = 4g + 2*b0 + b1, duplicated over b2. hidden<->decay exchange for
// h_new = tanh * exp(-decay*dt) is one more DPP row_ror:8 (lane^8 flips b3).
// h double-buffered in LDS as f16; ONE lgkm-only barrier per step.
// ---------------------------------------------------------------------------
__global__ __launch_bounds__(512, 2) void hawkes_rnn(
    const float* __restrict__ dt_g,  const float* __restrict__ h0,
    const float* __restrict__ W_hh,  const float* __restrict__ dec_W,
    const int*   __restrict__ seq_types,
    const float* __restrict__ tabH,  const float* __restrict__ tabD,
    float* __restrict__ out)
{
    __shared__ __align__(16) _Float16 h16[2][HD];
    __shared__ float dts[SEQ];
    __shared__ int   tys[SEQ];

    const int b   = blockIdx.x;
    const int tid = threadIdx.x;
    const int c   = tid & 15;         // K-chunk (8 h values)
    const int g   = tid >> 4;         // row quad, 0..31
    const int b0 = c & 1, b1 = (c >> 1) & 1, b2 = (c >> 2) & 1, b3 = (c >> 3) & 1;
    const int row = 4 * g + 2 * b0 + b1;   // row this lane finalizes

    // Stage dt / seq_types columns for this batch element.
    for (int t = tid; t < SEQ; t += 512) {
        dts[t] = dt_g[(size_t)t * BAT + b];
        tys[t] = seq_types[(size_t)t * BAT + b];
    }
    if (tid < HD) h16[0][tid] = (_Float16)h0[b * HD + tid];

    // Load + convert this lane's weight blocks to f16x2, pin in registers.
    // wH*: W_hh rows 4g..4g+3, cols 8c..8c+8.  wD*: dec_W h-part, same rows.
    const float* hrow = W_hh  + (size_t)(4 * g) * HD + 8 * c;
    const float* drow = dec_W + (size_t)(4 * g) * (KD + HD) + KD + 8 * c;
#define LW(D0,D1,D2,D3,P) { \
    const float4 _a = *reinterpret_cast<const float4*>(P);       \
    const float4 _b = *reinterpret_cast<const float4*>((P) + 4); \
    D0 = PK(_a.x, _a.y); D1 = PK(_a.z, _a.w);                    \
    D2 = PK(_b.x, _b.y); D3 = PK(_b.z, _b.w); }
    int wH00, wH01, wH02, wH03, wH10, wH11, wH12, wH13;
    int wH20, wH21, wH22, wH23, wH30, wH31, wH32, wH33;
    int wD00, wD01, wD02, wD03, wD10, wD11, wD12, wD13;
    int wD20, wD21, wD22, wD23, wD30, wD31, wD32, wD33;
    LW(wH00, wH01, wH02, wH03, hrow + 0 * HD)
    LW(wH10, wH11, wH12, wH13, hrow + 1 * HD)
    LW(wH20, wH21, wH22, wH23, hrow + 2 * HD)
    LW(wH30, wH31, wH32, wH33, hrow + 3 * HD)
    LW(wD00, wD01, wD02, wD03, drow + 0 * (KD + HD))
    LW(wD10, wD11, wD12, wD13, drow + 1 * (KD + HD))
    LW(wD20, wD21, wD22, wD23, drow + 2 * (KD + HD))
    LW(wD30, wD31, wD32, wD33, drow + 3 * (KD + HD))
#undef LW
    PIN(wH00); PIN(wH01); PIN(wH02); PIN(wH03);
    PIN(wH10); PIN(wH11); PIN(wH12); PIN(wH13);
    PIN(wH20); PIN(wH21); PIN(wH22); PIN(wH23);
    PIN(wH30); PIN(wH31); PIN(wH32); PIN(wH33);
    PIN(wD00); PIN(wD01); PIN(wD02); PIN(wD03);
    PIN(wD10); PIN(wD11); PIN(wD12); PIN(wD13);
    PIN(wD20); PIN(wD21); PIN(wD22); PIN(wD23);
    PIN(wD30); PIN(wD31); PIN(wD32); PIN(wD33);

    const float* tabp = (b3 ? tabD : tabH) + row;

    __syncthreads();   // staging + h16[0] visible

    // Strength-reduced output pointers (advance by BAT*HD per step).
    const size_t base = (size_t)b * HD + row;
    float* hid_p = out + base;
    float* dec_p = out + (size_t)SEQ * BAT * HD + base;
    float* hti_p = out + (size_t)2 * SEQ * BAT * HD + base;

    // Table prefetch pipeline (2 steps ahead; tables are L2-resident).
    float tab_cur = tabp[tys[0] * HD];
    float tab_nxt = tabp[tys[1] * HD];
    int p = 0;

    for (int t = 0; t < SEQ; ++t) {
        const int   tpf    = (t + 2 < SEQ) ? tys[t + 2] : 0;
        const float tab_pf = tabp[tpf * HD];   // issue now, use at t+2
        const float dtv    = dts[t];

        // ONE ds_read_b128: 8 f16 of h = this lane's whole K-chunk.
        const int4 hv = *reinterpret_cast<const int4*>(&h16[p][c * 8]);

        float aH0 = 0.f, aH1 = 0.f, aH2 = 0.f, aH3 = 0.f;
        float aD0 = 0.f, aD1 = 0.f, aD2 = 0.f, aD3 = 0.f;
#define DOT4(A, W0, W1, W2, W3) \
        A = fdot2(W0, hv.x, A); A = fdot2(W1, hv.y, A); \
        A = fdot2(W2, hv.z, A); A = fdot2(W3, hv.w, A);
        DOT4(aH0, wH00, wH01, wH02, wH03)
        DOT4(aH1, wH10, wH11, wH12, wH13)
        DOT4(aH2, wH20, wH21, wH22, wH23)
        DOT4(aH3, wH30, wH31, wH32, wH33)
        DOT4(aD0, wD00, wD01, wD02, wD03)
        DOT4(aD1, wD10, wD11, wD12, wD13)
        DOT4(aD2, wD20, wD21, wD22, wD23)
        DOT4(aD3, wD30, wD31, wD32, wD33)
#undef DOT4

        // Value-halving butterfly over the 16 chunk lanes.
        // S1 (xor1, DPP): 8 -> 4 (resolve row bit b0: keep rows {0,1} or {2,3})
        float BH0 = dpp_add<0xB1>(b0 ? aH2 : aH0, b0 ? aH0 : aH2);
        float BH1 = dpp_add<0xB1>(b0 ? aH3 : aH1, b0 ? aH1 : aH3);
        float BD0 = dpp_add<0xB1>(b0 ? aD2 : aD0, b0 ? aD0 : aD2);
        float BD1 = dpp_add<0xB1>(b0 ? aD3 : aD1, b0 ? aD1 : aD3);
        // S2 (xor2, DPP): 4 -> 2 (resolve row bit b1)
        float CH = dpp_add<0x4E>(b1 ? BH1 : BH0, b1 ? BH0 : BH1);
        float CD = dpp_add<0x4E>(b1 ? BD1 : BD0, b1 ? BD0 : BD1);
        // S3 (xor8, DPP row_ror:8): 2 -> 1 (resolve type = b3)
        float D = dpp_add<0x128>(b3 ? CD : CH, b3 ? CH : CD);
        // S4 (xor4, ds_swizzle): complete the 16-lane sum (b2 pairs)
        float sv = D + swz<XOR4>(D);
        sv += tab_cur;

        // Both activation paths (lanes diverge on b3; compute both + select).
        const float e2 = __expf(2.f * sv);
        const float vh = 1.f - __fdividef(2.f, e2 + 1.f);      // tanh(sv)
        const float z  = 10.f * sv;
        const float em = __expf(-fabsf(z));
        const float sp = 0.1f * (fmaxf(z, 0.f) + __logf(1.f + em)); // softplus10
        const float vd = __expf(-sp * dtv);                    // decay factor
        const float v  = b3 ? vd : vh;

        // hidden <-> decay exchange (flip b3): one more DPP row_ror:8.
        const float cross = dpp_mov<0x128>(v);
        const float hnew  = v * cross;

        if (b2 == 0) {                       // dedupe the b2 copies
            if (b3 == 0) {
                hid_p[0] = v;
                hti_p[0] = hnew;
                h16[p ^ 1][row] = (_Float16)hnew;
            } else {
                dec_p[0] = sp;
            }
        }
        hid_p += BAT * HD; hti_p += BAT * HD; dec_p += BAT * HD;

        tab_cur = tab_nxt;
        tab_nxt = tab_pf;
        STEP_BARRIER();   // lgkm-only: h(t+1) visible, stores stay in flight
        p ^= 1;
    }
}

extern "C" void kernel_launch(void* const* d_in, const int* in_sizes, int n_in,
                              void* d_out, int out_size, void* d_ws, size_t ws_size,
                              hipStream_t stream) {
    const float* dt        = (const float*)d_in[0];
    const float* h0        = (const float*)d_in[1];
    const float* embed_W   = (const float*)d_in[2];
    const float* W_ih      = (const float*)d_in[3];
    const float* b_ih      = (const float*)d_in[4];
    const float* W_hh      = (const float*)d_in[5];
    const float* b_hh      = (const float*)d_in[6];
    const float* dec_W     = (const float*)d_in[7];
    const float* dec_b     = (const float*)d_in[8];
    const int*   seq_types = (const int*)  d_in[9];
    float* out  = (float*)d_out;

    float* tabH = (float*)d_ws;                 // [65][128]
    float* tabD = tabH + (KD + 1) * HD;         // [65][128]

    precompute_tables<<<KD + 1, 128, 0, stream>>>(embed_W, W_ih, b_ih, b_hh,
                                                  dec_W, dec_b, tabH, tabD);
    hawkes_rnn<<<BAT, 512, 0, stream>>>(dt, h0, W_hh, dec_W, seq_types,
                                        tabH, tabD, out);
}

// Round 8
// 1006.767 us; speedup vs baseline: 1.3212x; 1.3212x over previous
//
#include <hip/hip_runtime.h>

// Problem constants (match reference)
#define SEQ 2048
#define BAT 256
#define KD  64
#define HD  128

typedef _Float16 half2v  __attribute__((ext_vector_type(2)));  // builtin fdot2 type
typedef __fp16   fp16x2  __attribute__((ext_vector_type(2)));  // cvt_pkrtz return type

// DPP helpers. CTRL: 0xB1 = quad_perm(1,0,3,2) = lane^1; 0x4E = quad_perm(2,3,0,1)
// = lane^2; 0x128 = row_ror:8 = lane^8 within 16-lane row; 0x124/0x12C =
// row_ror:4 / row_ror:12 (together + select = lane^4 exchange).
template<int CTRL>
__device__ __forceinline__ float dpp_add(float keep, float send) {
    const int r = __builtin_amdgcn_update_dpp(0, __float_as_int(send),
                                              CTRL, 0xF, 0xF, true);
    return keep + __int_as_float(r);
}
template<int CTRL>
__device__ __forceinline__ float dpp_mov(float send) {
    const int r = __builtin_amdgcn_update_dpp(0, __float_as_int(send),
                                              CTRL, 0xF, 0xF, true);
    return __int_as_float(r);
}

// Pack two f32 -> f16x2 bits (v_cvt_pkrtz_f16_f32).
__device__ __forceinline__ int PK(float a, float b) {
    fp16x2 p = __builtin_amdgcn_cvt_pkrtz(a, b);
    return __builtin_bit_cast(int, p);
}

// f32 += dot2(f16x2, f16x2) — v_dot2_f32_f16 (2 MACs / inst), f32 accumulate.
__device__ __forceinline__ float fdot2(int w, int h, float c) {
#if __has_builtin(__builtin_amdgcn_fdot2)
    return __builtin_amdgcn_fdot2(__builtin_bit_cast(half2v, w),
                                  __builtin_bit_cast(half2v, h), c, false);
#else
    half2v wv = __builtin_bit_cast(half2v, w), hv = __builtin_bit_cast(half2v, h);
    return fmaf((float)wv[1], (float)hv[1], fmaf((float)wv[0], (float)hv[0], c));
#endif
}

// Pin a scalar into a register (loads can't sink past the volatile asm).
#define PIN(x) asm volatile("" : "+v"(x))

// LDS-visibility-only barrier: does NOT drain vmcnt (global stores stay in
// flight; they need no ordering with the barrier).
#define STEP_BARRIER() do {                                   \
    asm volatile("s_waitcnt lgkmcnt(0)" ::: "memory");        \
    __builtin_amdgcn_s_barrier();                             \
    asm volatile("" ::: "memory");                            \
} while (0)

// ---------------------------------------------------------------------------
// Kernel 1: precompute type-dependent tables into d_ws (f32).
//   tabH[ty][r] = sum_k embed_W[ty][k]*W_ih[r][k] + b_ih[r] + b_hh[r]
//   tabD[ty][r] = sum_k embed_W[ty][k]*dec_W[r][k] + dec_b[r]
// ---------------------------------------------------------------------------
__global__ __launch_bounds__(128) void precompute_tables(
    const float* __restrict__ embed_W, const float* __restrict__ W_ih,
    const float* __restrict__ b_ih,    const float* __restrict__ b_hh,
    const float* __restrict__ dec_W,   const float* __restrict__ dec_b,
    float* __restrict__ tabH, float* __restrict__ tabD)
{
    __shared__ float x[KD];
    const int ty = blockIdx.x;   // 0..64 (row 64 = padding, embed row is zero)
    const int r  = threadIdx.x;  // 0..127
    if (r < KD) x[r] = embed_W[ty * KD + r];
    __syncthreads();
    float ah = 0.f, ad = 0.f;
#pragma unroll
    for (int k = 0; k < KD; ++k) {
        const float xv = x[k];
        ah += xv * W_ih[r * KD + k];
        ad += xv * dec_W[r * (KD + HD) + k];
    }
    tabH[ty * HD + r] = ah + b_ih[r] + b_hh[r];
    tabD[ty * HD + r] = ad + dec_b[r];
}

// ---------------------------------------------------------------------------
// Kernel 2: persistent per-batch-element recurrence. One WG per batch elem,
// 512 threads = 8 waves. Lane bits (lane = tid&63):
//   b0(bit0), b1(bit1): row-low bits AND chunk bits 0,1 (value-halving)
//   b2(bit2): type (0=hidden/W_hh, 1=decay/dec_W)
//   b3(bit3): chunk bit 2 / duplicate tag
//   bits4-5 + wave: row quad G = wave*4 + ((lane>>4)&3)
// chunk = b0 | b1<<1 | b3<<2  (8 chunks x 16 h-elems, 2 ds_read_b128/lane)
// row   = 4G + 2*b0 + b1
// Reduction (all DPP, no ds_swizzle): xor1 halve, xor2 halve, xor8 plain add
// (row_ror:8). Type exchange lane^4 = row_ror:4/12 + select. Each lane does
// EXACTLY ONE output task: (b2,b3) = (0,0) store hidden, (0,1) store
// hidden_ti, (1,0) store decay, (1,1) LDS-write h_new.
// h double-buffered in LDS f16; ONE lgkm-only barrier per step; 2x unrolled.
// ---------------------------------------------------------------------------
__global__ __launch_bounds__(512, 2) void hawkes_rnn(
    const float* __restrict__ dt_g,  const float* __restrict__ h0,
    const float* __restrict__ W_hh,  const float* __restrict__ dec_W,
    const int*   __restrict__ seq_types,
    const float* __restrict__ tabH,  const float* __restrict__ tabD,
    float* __restrict__ out)
{
    __shared__ __align__(16) _Float16 h16[2][HD];
    __shared__ float dts[SEQ];
    __shared__ int   tys[SEQ + 2];

    const int b    = blockIdx.x;
    const int tid  = threadIdx.x;
    const int lane = tid & 63;
    const int b0 = lane & 1, b1 = (lane >> 1) & 1;
    const int b2 = (lane >> 2) & 1, b3 = (lane >> 3) & 1;
    const int G    = (tid >> 6) * 4 + ((lane >> 4) & 3);  // row quad 0..31
    const int row  = 4 * G + 2 * b0 + b1;
    const int chunk = b0 | (b1 << 1) | (b3 << 2);         // h-col block /16
    const bool cls3 = (b2 & b3);                          // LDS-writer lane

    // Stage dt / seq_types columns for this batch element.
    for (int t = tid; t < SEQ; t += 512) {
        dts[t] = dt_g[(size_t)t * BAT + b];
        tys[t] = seq_types[(size_t)t * BAT + b];
    }
    if (tid < 2) tys[SEQ + tid] = 0;          // prefetch-pad
    if (tid < HD) h16[0][tid] = (_Float16)h0[b * HD + tid];

    // Load + convert this lane's weight block (4 rows x 16 cols) to f16x2.
    const size_t rstr = b2 ? (size_t)(KD + HD) : (size_t)HD;
    const float* wb = (b2 ? (dec_W + KD) : W_hh) + (size_t)(4 * G) * rstr
                      + chunk * 16;
#define LW8(D0,D1,D2,D3,D4,D5,D6,D7,P) { \
    const float4 _a = *reinterpret_cast<const float4*>(P);        \
    const float4 _b = *reinterpret_cast<const float4*>((P) + 4);  \
    const float4 _c = *reinterpret_cast<const float4*>((P) + 8);  \
    const float4 _d = *reinterpret_cast<const float4*>((P) + 12); \
    D0 = PK(_a.x,_a.y); D1 = PK(_a.z,_a.w); D2 = PK(_b.x,_b.y); D3 = PK(_b.z,_b.w); \
    D4 = PK(_c.x,_c.y); D5 = PK(_c.z,_c.w); D6 = PK(_d.x,_d.y); D7 = PK(_d.z,_d.w); }
    int w00,w01,w02,w03,w04,w05,w06,w07;
    int w10,w11,w12,w13,w14,w15,w16,w17;
    int w20,w21,w22,w23,w24,w25,w26,w27;
    int w30,w31,w32,w33,w34,w35,w36,w37;
    LW8(w00,w01,w02,w03,w04,w05,w06,w07, wb + 0 * rstr)
    LW8(w10,w11,w12,w13,w14,w15,w16,w17, wb + 1 * rstr)
    LW8(w20,w21,w22,w23,w24,w25,w26,w27, wb + 2 * rstr)
    LW8(w30,w31,w32,w33,w34,w35,w36,w37, wb + 3 * rstr)
#undef LW8
    PIN(w00);PIN(w01);PIN(w02);PIN(w03);PIN(w04);PIN(w05);PIN(w06);PIN(w07);
    PIN(w10);PIN(w11);PIN(w12);PIN(w13);PIN(w14);PIN(w15);PIN(w16);PIN(w17);
    PIN(w20);PIN(w21);PIN(w22);PIN(w23);PIN(w24);PIN(w25);PIN(w26);PIN(w27);
    PIN(w30);PIN(w31);PIN(w32);PIN(w33);PIN(w34);PIN(w35);PIN(w36);PIN(w37);

    const float* tabp = (b2 ? tabD : tabH) + row;

    // Per-lane 32-bit element offset for the single global store this lane
    // owns (advanced by BAT*HD per step). Class 3 never stores (value unused).
    unsigned off = (unsigned)(b2 ? (b3 ? 0u : (unsigned)SEQ * BAT * HD)
                                 : (b3 ? 2u * SEQ * BAT * HD : 0u))
                   + (unsigned)(b * HD + row);

    __syncthreads();   // staging + h16[0] visible

    // Table prefetch pipeline (2 steps ahead; tables are L2-resident).
    float tab_cur = tabp[tys[0] * HD];
    float tab_nxt = tabp[tys[1] * HD];

#define DOT8(A,W0,W1,W2,W3,W4,W5,W6,W7) \
    A = fdot2(W0, hv0.x, A); A = fdot2(W1, hv0.y, A); \
    A = fdot2(W2, hv0.z, A); A = fdot2(W3, hv0.w, A); \
    A = fdot2(W4, hv1.x, A); A = fdot2(W5, hv1.y, A); \
    A = fdot2(W6, hv1.z, A); A = fdot2(W7, hv1.w, A);

#define STEP(P, TT) { \
    const float tab_pf = tabp[tys[(TT) + 2] * HD];   /* use at TT+2 */ \
    const float dtv    = dts[TT]; \
    const int4 hv0 = *reinterpret_cast<const int4*>(&h16[P][chunk * 16]); \
    const int4 hv1 = *reinterpret_cast<const int4*>(&h16[P][chunk * 16 + 8]); \
    float a0 = 0.f, a1 = 0.f, a2 = 0.f, a3 = 0.f; \
    DOT8(a0, w00,w01,w02,w03,w04,w05,w06,w07) \
    DOT8(a1, w10,w11,w12,w13,w14,w15,w16,w17) \
    DOT8(a2, w20,w21,w22,w23,w24,w25,w26,w27) \
    DOT8(a3, w30,w31,w32,w33,w34,w35,w36,w37) \
    /* value-halving: xor1 resolves row-bit1, xor2 resolves row-bit0 */ \
    const float t0 = dpp_add<0xB1>(b0 ? a2 : a0, b0 ? a0 : a2); \
    const float t1 = dpp_add<0xB1>(b0 ? a3 : a1, b0 ? a1 : a3); \
    const float u  = dpp_add<0x4E>(b1 ? t1 : t0, b1 ? t0 : t1); \
    /* xor8 plain add completes the 8-chunk sum */ \
    const float sv = dpp_add<0x128>(u, u) + tab_cur; \
    /* activations (branchless; all lanes both paths) */ \
    const float e2 = __expf(2.f * sv); \
    const float vh = 1.f - __fdividef(2.f, e2 + 1.f);            /* tanh */ \
    const float z  = 10.f * sv; \
    const float em = __expf(-fabsf(z)); \
    const float sp = 0.1f * (fmaxf(z, 0.f) + __logf(1.f + em));  /* softplus10 */ \
    const float vd = __expf(-sp * dtv); \
    const float v  = b2 ? vd : vh; \
    /* type exchange lane^4: row_ror:4 / row_ror:12 + select */ \
    const float x4  = dpp_mov<0x124>(v); \
    const float x12 = dpp_mov<0x12C>(v); \
    const float cross = b2 ? x12 : x4; \
    const float hnew  = v * cross; \
    if (cls3) { \
        h16[(P) ^ 1][row] = (_Float16)hnew; \
    } else { \
        const float stv = b2 ? sp : (b3 ? hnew : v); \
        out[off] = stv; \
    } \
    off += BAT * HD; \
    tab_cur = tab_nxt; \
    tab_nxt = tab_pf; \
    STEP_BARRIER(); \
}

    for (int t = 0; t < SEQ; t += 2) {
        STEP(0, t)
        STEP(1, t + 1)
    }
#undef STEP
#undef DOT8
}

extern "C" void kernel_launch(void* const* d_in, const int* in_sizes, int n_in,
                              void* d_out, int out_size, void* d_ws, size_t ws_size,
                              hipStream_t stream) {
    const float* dt        = (const float*)d_in[0];
    const float* h0        = (const float*)d_in[1];
    const float* embed_W   = (const float*)d_in[2];
    const float* W_ih      = (const float*)d_in[3];
    const float* b_ih      = (const float*)d_in[4];
    const float* W_hh      = (const float*)d_in[5];
    const float* b_hh      = (const float*)d_in[6];
    const float* dec_W     = (const float*)d_in[7];
    const float* dec_b     = (const float*)d_in[8];
    const int*   seq_types = (const int*)  d_in[9];
    float* out  = (float*)d_out;

    float* tabH = (float*)d_ws;                 // [65][128]
    float* tabD = tabH + (KD + 1) * HD;         // [65][128]

    precompute_tables<<<KD + 1, 128, 0, stream>>>(embed_W, W_ih, b_ih, b_hh,
                                                  dec_W, dec_b, tabH, tabD);
    hawkes_rnn<<<BAT, 512, 0, stream>>>(dt, h0, W_hh, dec_W, seq_types,
                                        tabH, tabD, out);
}